// Round 10
// baseline (4875.947 us; speedup 1.0000x reference)
//
#include <hip/hip_runtime.h>

// LSTM fused kernel for MI355X (gfx950) — round 10: in-register gates.
// 256 blocks x 512 threads (8 waves, 2 waves/SIMD). Group = measured XCD
// (32 blocks); group owns 32 batch rows split into tiles A/B (16 rows),
// alternated per slot (hides inter-block flag latency).
// Wave w owns 4 h-cols x 4 gates (16 z-cols, Breg[40]=160 regs stationary).
// After K-loop, shfl_xor(4/8/12) gathers (g,i,f,o) per (row,col) -> LSTM
// update fully in registers; c lives in registers (2 tiles x f32x4).
// No zbuf, no LDS c: 3 syncthreads/slot. x staged pre-barrier.
// Sync: relaxed agent flags + buffer_inv sc0 acquire (xloc), early-poll of
// next slot's flags after K-loop; threadfence fallback. Guards 1<<18.
// Workspace (~12.4 MB):
//   WT fp16 [4096][1280] @0   WphT fp16 [256][1024] @10485760
//   hbuf fp16 [2][256][1024] @11010048   lg f32 [256][256] @12058624
//   cnt u32 [8][2][32] @12320768   tick u32 [8] @12322816

typedef _Float16 f16;
typedef _Float16 f16x8 __attribute__((ext_vector_type(8)));
typedef _Float16 f16x4 __attribute__((ext_vector_type(4)));
typedef float f32x4 __attribute__((ext_vector_type(4)));
typedef unsigned int u32;

#define WS_WT    0
#define WS_WPHT  10485760
#define WS_HBUF  11010048
#define WS_LG    12058624
#define WS_CNT   12320768
#define WS_TICK  12322816

__device__ __forceinline__ float sigm(float v) { return 1.0f / (1.0f + __expf(-v)); }
__device__ __forceinline__ float tanhfast(float v) {
  float t = __expf(-2.0f * fabsf(v));
  float r = (1.0f - t) / (1.0f + t);
  return v < 0.0f ? -r : r;
}

// ---------- prep: WT[n][k], n=gate*1024+j (z-col), k<1024 -> Wh[k][j], else Wx[k-1024][j]
__global__ __launch_bounds__(256) void prep_wt(
    const float* __restrict__ Wgh, const float* __restrict__ Wih,
    const float* __restrict__ Wfh, const float* __restrict__ Woh,
    const float* __restrict__ Wgx, const float* __restrict__ Wix,
    const float* __restrict__ Wfx, const float* __restrict__ Wox,
    f16* __restrict__ WT)
{
  __shared__ float tile[32][33];
  int bid = blockIdx.x;
  int gate = bid / 1280;
  int rem  = bid % 1280;
  int jt = rem / 40, kt = rem % 40;
  const float* srcH = (gate==0)?Wgh:(gate==1)?Wih:(gate==2)?Wfh:Woh;
  const float* srcX = (gate==0)?Wgx:(gate==1)?Wix:(gate==2)?Wfx:Wox;
  const float* src = (kt < 32) ? (srcH + (size_t)(kt*32)*1024)
                               : (srcX + (size_t)(kt*32 - 1024)*1024);
  int t = threadIdx.x;
  {
    int jl = t & 31, kg = t >> 5;
#pragma unroll
    for (int it = 0; it < 4; ++it) {
      int kl = kg + it*8;
      tile[kl][jl] = src[(size_t)kl*1024 + jt*32 + jl];
    }
  }
  __syncthreads();
  {
    int kl = t & 31, jg = t >> 5;
#pragma unroll
    for (int it = 0; it < 4; ++it) {
      int jl2 = jg + it*8;
      WT[(size_t)(gate*1024 + jt*32 + jl2)*1280 + kt*32 + kl] = (f16)tile[kl][jl2];
    }
  }
}

// ---------- prep: WphT[oc][k] = W_ph[k][oc], fp16
__global__ __launch_bounds__(256) void prep_wph(const float* __restrict__ Wph,
                                                f16* __restrict__ WphT)
{
  __shared__ float tile[32][33];
  int bid = blockIdx.x;
  int jt = bid & 7, kt = bid >> 3;
  int t = threadIdx.x;
  {
    int jl = t & 31, kg = t >> 5;
#pragma unroll
    for (int it = 0; it < 4; ++it) {
      int kl = kg + it*8;
      tile[kl][jl] = Wph[(size_t)(kt*32 + kl)*256 + jt*32 + jl];
    }
  }
  __syncthreads();
  {
    int kl = t & 31, jg = t >> 5;
#pragma unroll
    for (int it = 0; it < 4; ++it) {
      int jl2 = jg + it*8;
      WphT[(size_t)(jt*32 + jl2)*1024 + kt*32 + kl] = (f16)tile[kl][jl2];
    }
  }
}

// ---------- main persistent LSTM kernel
// LDS: A-tile[2] [16][1280]f16 swizzled @0/@40960, bcast @81920 (ticket,xloc).
__global__ __launch_bounds__(512, 2) void lstm_main(
    const float* __restrict__ x, const f16* __restrict__ WT,
    const f16* __restrict__ WphT, f16* __restrict__ hbuf,
    const float* __restrict__ bgp, const float* __restrict__ bip,
    const float* __restrict__ bfp, const float* __restrict__ bop,
    const float* __restrict__ bpp, float* __restrict__ lg,
    u32* __restrict__ cnt, u32* __restrict__ tick, float* __restrict__ out)
{
  __shared__ __align__(16) char smem[81936];
  const int tid  = threadIdx.x;
  const int lane = tid & 63;
  const int wv   = tid >> 6;       // wave owns cols cg*32 + wv*4 .. +3 (all gates)
  const int l15 = lane & 15, l4 = lane >> 4;

  // ---- measure XCD, take ticket on per-XCD counter
  u32 myxcd;
  asm volatile("s_getreg_b32 %0, hwreg(HW_REG_XCC_ID)" : "=s"(myxcd));
  myxcd &= 7u;
  if (tid == 0) {
    u32 t = __hip_atomic_fetch_add(tick + myxcd, 1u,
                                   __ATOMIC_RELAXED, __HIP_MEMORY_SCOPE_AGENT);
    *(volatile u32*)(smem + 81920) = t;
  }
  if (wv == 0) {
    u32 v = 0;
    int guard = 0;
    for (;;) {
      v = (lane < 8) ? __hip_atomic_load(tick + lane, __ATOMIC_RELAXED,
                                         __HIP_MEMORY_SCOPE_AGENT) : 0u;
      u32 sum = v;
      sum += __shfl_xor(sum, 1);
      sum += __shfl_xor(sum, 2);
      sum += __shfl_xor(sum, 4);
      if (__shfl(sum, 0) == 256u) break;
      __builtin_amdgcn_s_sleep(1);
      if (++guard > (1 << 20)) break;
    }
    int even = __all((lane < 8) ? (v == 32u) : 1);
    if (lane == 0) *(volatile u32*)(smem + 81924) = (u32)even;
  }
  __syncthreads();
  const bool xloc = (*(volatile u32*)(smem + 81924)) != 0u;
  const u32 myticket = *(volatile u32*)(smem + 81920);
  const int xg = xloc ? (int)myxcd    : (blockIdx.x & 7);   // batch-tile group
  const int cg = xloc ? (int)myticket : (blockIdx.x >> 3);  // column slice 0..31
  u32* flg = cnt + xg*64;           // [tileA flags 0..31][tileB flags 32..63]

  // ---- weight-stationary B fragments: lane l15 -> gate l15>>2, col wv*4+(l15&3)
  f16x8 Breg[40];
  {
    const int ncol = (l15 >> 2)*1024 + cg*32 + wv*4 + (l15 & 3);
    const f16* wb = WT + (size_t)ncol*1280 + l4*8;
#pragma unroll
    for (int kk = 0; kk < 40; ++kk) {
      Breg[kk] = *(const f16x8*)(wb + kk*32);
      asm volatile("" : "+v"(Breg[kk]));   // opaque: no remat, stays live
    }
  }

  // per-thread biases for col cg*32 + wv*4 + (l15&3)
  const int bcol = cg*32 + wv*4 + (l15 & 3);
  const float bgr = bgp[bcol], bir = bip[bcol], bfr = bfp[bcol], bor = bop[bcol];

  // A-frag addressing: addr = Abase + ((l15*2560 + l4*16 + kk*64) ^ ((l15&7)<<4))
  const u32 aoff0 = (u32)l15*2560u + (u32)(l4*16);
  const u32 aswz  = ((u32)(l15 & 7)) << 4;
  // staging indices: 16 rows x 32 segs (512 threads)
  const int srow = tid >> 5;       // 0..15
  const int sseg = tid & 31;       // 0..31
  const u32 swzr = ((u32)(srow & 7) << 4);

  // c state in registers, one f32x4 per tile (rows l4*4+i, col wv*4+l15 for l15<4)
  f32x4 cA = {}, cB = {};

  u32 pre = 0xFFFFFFFFu;
  bool preOK = false;

#pragma unroll 1
  for (int slot = 0; slot < 1024; ++slot) {
    const int T = slot & 1, s = slot >> 1;
    const u32 Abase = (u32)T * 40960u;
    u32* flgT = flg + T*32;
    const int grow = xg*32 + T*16 + srow;

    // ---- x stage PRE-BARRIER (tile-T x region is dead here; hazard cleared
    // by slot t-2's drain sync). Overlaps the spin/flag latency.
    {
      const float* xsrc = x + ((size_t)grow*512 + (size_t)s)*256;
      float4 xv0 = *(const float4*)(xsrc + (sseg     )*4);
      float4 xv1 = *(const float4*)(xsrc + (sseg + 32)*4);
      f16x4 hv;
      hv[0] = (f16)xv0.x; hv[1] = (f16)xv0.y; hv[2] = (f16)xv0.z; hv[3] = (f16)xv0.w;
      *(f16x4*)(smem + Abase + ((srow*2560u + 2048u + 8u*(u32)(sseg     )) ^ swzr)) = hv;
      hv[0] = (f16)xv1.x; hv[1] = (f16)xv1.y; hv[2] = (f16)xv1.z; hv[3] = (f16)xv1.w;
      *(f16x4*)(smem + Abase + ((srow*2560u + 2048u + 8u*(u32)(sseg + 32)) ^ swzr)) = hv;
    }
    // ---- tile-T barrier: all 32 blocks finished tile-T step s-1
    if (s > 0) {
      if (wv == 0) {
        if (!preOK) {
          const u32 tgt = (u32)s;
          u32 v = tgt;
          int guard = 0;
          for (;;) {
            if (lane < 32)
              v = __hip_atomic_load(flgT + lane, __ATOMIC_RELAXED,
                                    __HIP_MEMORY_SCOPE_AGENT);
            if (__all(v >= tgt)) break;
            __builtin_amdgcn_s_sleep(1);
            if (++guard > (1 << 18)) break;
          }
        }
        if (lane == 0) {
          if (xloc) {
            asm volatile("buffer_inv sc0\n\ts_waitcnt vmcnt(0)" ::: "memory");
          } else {
            __threadfence();
          }
        }
      }
    }
    __syncthreads();
    // ---- stage tile-T h part [16 rows x 1024] fp16, XOR-swizzled
    {
      const f16* hsrc = hbuf + (size_t)(s & 1)*262144 + (size_t)grow*1024;
#pragma unroll
      for (int j = 0; j < 4; ++j) {
        int chunk = sseg + 32*j;                       // 16B chunk of h row
        uint4 v = *(const uint4*)(hsrc + chunk*8);
        *(uint4*)(smem + Abase + ((srow*2560u + 16u*(u32)chunk) ^ swzr)) = v;
      }
    }
    __syncthreads();
    // ---- K loop: full K=1280, 16 rows, 16 z-cols per wave (2 acc chains)
    f32x4 accA = {}, accB = {};
#pragma unroll
    for (int kk = 0; kk < 40; kk += 2) {
      f16x8 av0 = *(const f16x8*)(smem + Abase + ((aoff0 + (u32)kk*64u)       ^ aswz));
      f16x8 av1 = *(const f16x8*)(smem + Abase + ((aoff0 + (u32)(kk+1)*64u)   ^ aswz));
      accA = __builtin_amdgcn_mfma_f32_16x16x32_f16(av0, Breg[kk],   accA, 0, 0, 0);
      accB = __builtin_amdgcn_mfma_f32_16x16x32_f16(av1, Breg[kk+1], accB, 0, 0, 0);
    }
    // ---- early poll for next slot (L3 latency covered by gates + drain sync)
    {
      const int nS = (slot + 1) >> 1, nT = (slot + 1) & 1;
      pre = 0xFFFFFFFFu;
      if (wv == 0 && nS > 0 && nS < 512 && lane < 32)
        pre = __hip_atomic_load(flg + nT*32 + lane, __ATOMIC_RELAXED,
                                __HIP_MEMORY_SCOPE_AGENT);
    }
    // ---- gates fully in registers: gather (g,i,f,o) via shfl_xor
    {
      f32x4 z;
#pragma unroll
      for (int i = 0; i < 4; ++i) z[i] = accA[i] + accB[i];
      f32x4 cc = T ? cB : cA;
      f16* hw = hbuf + (size_t)((s & 1) ^ 1)*262144;
      const int hcol = cg*32 + wv*4 + l15;             // valid for l15 < 4
#pragma unroll
      for (int i = 0; i < 4; ++i) {
        float zg = z[i];
        float zi = __shfl_xor(z[i], 4);
        float zf = __shfl_xor(z[i], 8);
        float zo = __shfl_xor(z[i], 12);
        if (l15 < 4) {
          float gv = tanhfast(zg + bgr);
          float iv = sigm(zi + bir);
          float fv = sigm(zf + bfr);
          float ov = sigm(zo + bor);
          float cn = gv*iv + cc[i]*fv;
          cc[i] = cn;
          float hv = tanhfast(cn) * ov;
          hw[(size_t)(xg*32 + T*16 + l4*4 + i)*1024 + hcol] = (f16)hv;
        }
      }
      if (T) cB = cc; else cA = cc;
    }
    __syncthreads();   // drains h stores (vmcnt) before flag release
    if (tid == 0) {
      if (!xloc) __threadfence();
      __hip_atomic_store(flgT + cg, (u32)(s + 1),
                         __ATOMIC_RELAXED, __HIP_MEMORY_SCOPE_AGENT);
    }
    if (wv == 0) {
      const int nS = (slot + 1) >> 1;
      preOK = (nS == 0) || (nS >= 512) || __all(pre >= (u32)nS);
    }
  }

  // ---- epilogue: wait both tiles at 512, logits = h @ WphT + bp
  if (wv == 0) {
    u32 v = 512u;
    int guard = 0;
    for (;;) {
      v = __hip_atomic_load(flg + lane, __ATOMIC_RELAXED,
                            __HIP_MEMORY_SCOPE_AGENT);   // lanes 0-63 = A,B
      if (__all(v >= 512u)) break;
      __builtin_amdgcn_s_sleep(1);
      if (++guard > (1 << 18)) break;
    }
    if (lane == 0) {
      if (xloc) { asm volatile("buffer_inv sc0\n\ts_waitcnt vmcnt(0)" ::: "memory"); }
      else      { __threadfence(); }
    }
  }
  __syncthreads();
  {
#pragma unroll 1
    for (int p = 0; p < 32; ++p) {
      int rowl = wv*4 + (p >> 3);
      int oc   = p & 7;
      const f16* hp = hbuf + (size_t)(xg*32 + rowl)*1024 + lane*16;  // buf 0 = h_T
      const f16* wp = WphT + (size_t)(cg*8 + oc)*1024 + lane*16;
      f16x8 h0 = *(const f16x8*)hp;
      f16x8 h1 = *(const f16x8*)(hp + 8);
      f16x8 w0 = *(const f16x8*)wp;
      f16x8 w1 = *(const f16x8*)(wp + 8);
      float sum = 0.f;
#pragma unroll
      for (int q = 0; q < 8; ++q)
        sum += (float)h0[q]*(float)w0[q] + (float)h1[q]*(float)w1[q];
#pragma unroll
      for (int d = 1; d < 64; d <<= 1) sum += __shfl_xor(sum, d);
      if (lane == 0)
        lg[(size_t)(xg*32 + rowl)*256 + cg*8 + oc] = sum + bpp[cg*8 + oc];
    }
  }
  __syncthreads();   // drain lg stores
  if (tid == 0) {
    if (!xloc) __threadfence();
    __hip_atomic_store(flg + cg, 513u, __ATOMIC_RELAXED, __HIP_MEMORY_SCOPE_AGENT);
  }
  if (wv == 0) {
    u32 v = 513u;
    int guard = 0;
    for (;;) {
      if (lane < 32)
        v = __hip_atomic_load(flg + lane, __ATOMIC_RELAXED, __HIP_MEMORY_SCOPE_AGENT);
      if (__all(v >= 513u)) break;
      __builtin_amdgcn_s_sleep(1);
      if (++guard > (1 << 18)) break;
    }
    if (lane == 0) {
      if (xloc) { asm volatile("buffer_inv sc0\n\ts_waitcnt vmcnt(0)" ::: "memory"); }
      else      { __threadfence(); }
    }
  }
  __syncthreads();
  // ---- softmax: this block handles row xg*32+cg, wave 0 only
  if (tid < 64) {
    int rowg = xg*32 + cg;
    const float* lr = lg + (size_t)rowg*256;
    float v0 = lr[tid], v1 = lr[tid+64], v2 = lr[tid+128], v3 = lr[tid+192];
    float mx = fmaxf(fmaxf(v0, v1), fmaxf(v2, v3));
#pragma unroll
    for (int d = 1; d < 64; d <<= 1) mx = fmaxf(mx, __shfl_xor(mx, d));
    float e0 = __expf(v0-mx), e1 = __expf(v1-mx), e2 = __expf(v2-mx), e3 = __expf(v3-mx);
    float sm = e0+e1+e2+e3;
#pragma unroll
    for (int d = 1; d < 64; d <<= 1) sm += __shfl_xor(sm, d);
    float inv = 1.0f / sm;
    float* orow = out + (size_t)rowg*256;
    orow[tid]      = e0*inv;
    orow[tid+64]   = e1*inv;
    orow[tid+128]  = e2*inv;
    orow[tid+192]  = e3*inv;
  }
}

extern "C" void kernel_launch(void* const* d_in, const int* in_sizes, int n_in,
                              void* d_out, int out_size, void* d_ws, size_t ws_size,
                              hipStream_t stream) {
  (void)in_sizes; (void)n_in; (void)out_size; (void)ws_size;
  const float* x   = (const float*)d_in[0];
  const float* Wgx = (const float*)d_in[1];
  const float* Wgh = (const float*)d_in[2];
  const float* bg  = (const float*)d_in[3];
  const float* Wix = (const float*)d_in[4];
  const float* Wih = (const float*)d_in[5];
  const float* bi  = (const float*)d_in[6];
  const float* Wfx = (const float*)d_in[7];
  const float* Wfh = (const float*)d_in[8];
  const float* bf  = (const float*)d_in[9];
  const float* Wox = (const float*)d_in[10];
  const float* Woh = (const float*)d_in[11];
  const float* bo  = (const float*)d_in[12];
  const float* Wph = (const float*)d_in[13];
  const float* bp  = (const float*)d_in[14];

  char* ws = (char*)d_ws;
  f16*   WT   = (f16*)(ws + WS_WT);
  f16*   WphT = (f16*)(ws + WS_WPHT);
  f16*   hbuf = (f16*)(ws + WS_HBUF);
  float* lg   = (float*)(ws + WS_LG);
  u32*   cnt  = (u32*)(ws + WS_CNT);
  u32*   tick = (u32*)(ws + WS_TICK);

  // h0 = 0 (buffer 0); flags + tickets = 0 (replay-safe)
  hipMemsetAsync(hbuf, 0, 524288, stream);
  hipMemsetAsync(cnt, 0, 2048 + 64, stream);

  prep_wt<<<5120, 256, 0, stream>>>(Wgh, Wih, Wfh, Woh, Wgx, Wix, Wfx, Wox, WT);
  prep_wph<<<256, 256, 0, stream>>>(Wph, WphT);
  lstm_main<<<256, 512, 0, stream>>>(x, WT, WphT, hbuf,
                                     bg, bi, bf, bo, bp,
                                     lg, cnt, tick, (float*)d_out);
}

// Round 11
// 2504.787 us; speedup vs baseline: 1.9467x; 1.9467x over previous
//
#include <hip/hip_runtime.h>

// LSTM fused kernel for MI355X (gfx950) — round 11: round-9 base +
// (1) 4-bit XOR swizzle -> conflict-free A-tile ds_read_b128,
// (2) K-split wave pairs (gate=wv&3, kh=wv>>2) -> A-read volume halved,
//     partials summed in gates phase via 2-slot zbuf (192 B row stride),
// (3) pre-barrier x staging (proven r10).
// 256 blocks x 512 threads (8 waves, 2/SIMD). Group = measured XCD; 32 batch
// rows split into tiles A/B alternated per slot (hides flag latency).
// Sync: relaxed agent flags + buffer_inv sc0 acquire (xloc), early-poll;
// threadfence fallback; guards 1<<18.
// Workspace (~12.4 MB):
//   WT fp16 [4096][1280] @0   WphT fp16 [256][1024] @10485760
//   hbuf fp16 [2][256][1024] @11010048   lg f32 [256][256] @12058624
//   cnt u32 [8][2][32] @12320768   tick u32 [8] @12322816

typedef _Float16 f16;
typedef _Float16 f16x8 __attribute__((ext_vector_type(8)));
typedef _Float16 f16x4 __attribute__((ext_vector_type(4)));
typedef float f32x4 __attribute__((ext_vector_type(4)));
typedef unsigned int u32;

#define WS_WT    0
#define WS_WPHT  10485760
#define WS_HBUF  11010048
#define WS_LG    12058624
#define WS_CNT   12320768
#define WS_TICK  12322816

// LDS map: A-tile[2] [16][2560B] @0/@40960; zbuf[2][kh2][gate4][row16][col32]
// f32 row-stride 192 @81920 (24576/tile); c[2][16][32]f32 @131072; bcast @135168.
#define ZBASE 81920u
#define ZKH   12288u
#define ZGATE 3072u
#define ZROW  192u
#define CBUF  131072u
#define BCAST 135168

__device__ __forceinline__ float sigm(float v) { return 1.0f / (1.0f + __expf(-v)); }
__device__ __forceinline__ float tanhfast(float v) {
  float t = __expf(-2.0f * fabsf(v));
  float r = (1.0f - t) / (1.0f + t);
  return v < 0.0f ? -r : r;
}

// ---------- prep: WT[n][k], n=gate*1024+j (z-col), k<1024 -> Wh[k][j], else Wx[k-1024][j]
__global__ __launch_bounds__(256) void prep_wt(
    const float* __restrict__ Wgh, const float* __restrict__ Wih,
    const float* __restrict__ Wfh, const float* __restrict__ Woh,
    const float* __restrict__ Wgx, const float* __restrict__ Wix,
    const float* __restrict__ Wfx, const float* __restrict__ Wox,
    f16* __restrict__ WT)
{
  __shared__ float tile[32][33];
  int bid = blockIdx.x;
  int gate = bid / 1280;
  int rem  = bid % 1280;
  int jt = rem / 40, kt = rem % 40;
  const float* srcH = (gate==0)?Wgh:(gate==1)?Wih:(gate==2)?Wfh:Woh;
  const float* srcX = (gate==0)?Wgx:(gate==1)?Wix:(gate==2)?Wfx:Wox;
  const float* src = (kt < 32) ? (srcH + (size_t)(kt*32)*1024)
                               : (srcX + (size_t)(kt*32 - 1024)*1024);
  int t = threadIdx.x;
  {
    int jl = t & 31, kg = t >> 5;
#pragma unroll
    for (int it = 0; it < 4; ++it) {
      int kl = kg + it*8;
      tile[kl][jl] = src[(size_t)kl*1024 + jt*32 + jl];
    }
  }
  __syncthreads();
  {
    int kl = t & 31, jg = t >> 5;
#pragma unroll
    for (int it = 0; it < 4; ++it) {
      int jl2 = jg + it*8;
      WT[(size_t)(gate*1024 + jt*32 + jl2)*1280 + kt*32 + kl] = (f16)tile[kl][jl2];
    }
  }
}

// ---------- prep: WphT[oc][k] = W_ph[k][oc], fp16
__global__ __launch_bounds__(256) void prep_wph(const float* __restrict__ Wph,
                                                f16* __restrict__ WphT)
{
  __shared__ float tile[32][33];
  int bid = blockIdx.x;
  int jt = bid & 7, kt = bid >> 3;
  int t = threadIdx.x;
  {
    int jl = t & 31, kg = t >> 5;
#pragma unroll
    for (int it = 0; it < 4; ++it) {
      int kl = kg + it*8;
      tile[kl][jl] = Wph[(size_t)(kt*32 + kl)*256 + jt*32 + jl];
    }
  }
  __syncthreads();
  {
    int kl = t & 31, jg = t >> 5;
#pragma unroll
    for (int it = 0; it < 4; ++it) {
      int jl2 = jg + it*8;
      WphT[(size_t)(jt*32 + jl2)*1024 + kt*32 + kl] = (f16)tile[kl][jl2];
    }
  }
}

// ---------- main persistent LSTM kernel
__global__ __launch_bounds__(512, 2) void lstm_main(
    const float* __restrict__ x, const f16* __restrict__ WT,
    const f16* __restrict__ WphT, f16* __restrict__ hbuf,
    const float* __restrict__ bgp, const float* __restrict__ bip,
    const float* __restrict__ bfp, const float* __restrict__ bop,
    const float* __restrict__ bpp, float* __restrict__ lg,
    u32* __restrict__ cnt, u32* __restrict__ tick, float* __restrict__ out)
{
  __shared__ __align__(16) char smem[135184];
  const int tid  = threadIdx.x;
  const int lane = tid & 63;
  const int wv   = tid >> 6;       // wave: gate = wv&3, K-half = wv>>2
  const int gate = wv & 3;
  const int kh   = wv >> 2;
  const int l15 = lane & 15, l4 = lane >> 4;

  // ---- measure XCD, take ticket on per-XCD counter
  u32 myxcd;
  asm volatile("s_getreg_b32 %0, hwreg(HW_REG_XCC_ID)" : "=s"(myxcd));
  myxcd &= 7u;
  if (tid == 0) {
    u32 t = __hip_atomic_fetch_add(tick + myxcd, 1u,
                                   __ATOMIC_RELAXED, __HIP_MEMORY_SCOPE_AGENT);
    *(volatile u32*)(smem + BCAST) = t;
  }
  if (wv == 0) {
    u32 v = 0;
    int guard = 0;
    for (;;) {
      v = (lane < 8) ? __hip_atomic_load(tick + lane, __ATOMIC_RELAXED,
                                         __HIP_MEMORY_SCOPE_AGENT) : 0u;
      u32 sum = v;
      sum += __shfl_xor(sum, 1);
      sum += __shfl_xor(sum, 2);
      sum += __shfl_xor(sum, 4);
      if (__shfl(sum, 0) == 256u) break;
      __builtin_amdgcn_s_sleep(1);
      if (++guard > (1 << 20)) break;
    }
    int even = __all((lane < 8) ? (v == 32u) : 1);
    if (lane == 0) *(volatile u32*)(smem + BCAST + 4) = (u32)even;
  }
  __syncthreads();
  const bool xloc = (*(volatile u32*)(smem + BCAST + 4)) != 0u;
  const u32 myticket = *(volatile u32*)(smem + BCAST);
  const int xg = xloc ? (int)myxcd    : (blockIdx.x & 7);   // batch-tile group
  const int cg = xloc ? (int)myticket : (blockIdx.x >> 3);  // column slice 0..31
  u32* flg = cnt + xg*64;           // [tileA flags 0..31][tileB flags 32..63]

  // ---- weight-stationary B: 20 kk x 2 col-frags = 160 regs, K-half kh
  f16x8 Breg[20][2];
  {
    const f16* wb0 = WT + (size_t)(gate*1024 + cg*32 + l15)*1280 + kh*640 + l4*8;
    const f16* wb1 = wb0 + (size_t)16*1280;
#pragma unroll
    for (int kk = 0; kk < 20; ++kk) {
      Breg[kk][0] = *(const f16x8*)(wb0 + kk*32);
      asm volatile("" : "+v"(Breg[kk][0]));   // opaque: no remat, stays live
      Breg[kk][1] = *(const f16x8*)(wb1 + kk*32);
      asm volatile("" : "+v"(Breg[kk][1]));
    }
  }

  // per-thread bias (gate phase handles col = tid&31)
  const int bcol = cg*32 + (tid & 31);
  const float bgr = bgp[bcol], bir = bip[bcol], bfr = bfp[bcol], bor = bop[bcol];

  // A-frag addressing (4-bit swizzle, conflict-free):
  // addr = Abase + ((l15*2560 + kh*1280 + l4*16 + kk*64) ^ (l15<<4))
  const u32 aoff = (u32)l15*2560u + (u32)(kh*1280 + l4*16);
  const u32 aswz = (u32)l15 << 4;
  // staging indices: 16 rows x 32 segs (512 threads), 4-bit swizzle
  const int srow = tid >> 5;       // 0..15
  const int sseg = tid & 31;       // 0..31
  const u32 swzr = (u32)srow << 4;

  // zero c (both tiles: 1024 f32 / 512 thr = 2 each)
  *(float*)(smem + CBUF + tid*4) = 0.0f;
  *(float*)(smem + CBUF + 2048 + tid*4) = 0.0f;
  __syncthreads();

  u32 pre = 0xFFFFFFFFu;
  bool preOK = false;

#pragma unroll 1
  for (int slot = 0; slot < 1024; ++slot) {
    const int T = slot & 1, s = slot >> 1;
    const u32 Abase = (u32)T * 40960u;
    u32* flgT = flg + T*32;
    const int grow = xg*32 + T*16 + srow;

    // ---- x stage PRE-BARRIER (tile-T A region dead since slot-2's syncs)
    {
      const float* xsrc = x + ((size_t)grow*512 + (size_t)s)*256;
      float4 xv0 = *(const float4*)(xsrc + (sseg     )*4);
      float4 xv1 = *(const float4*)(xsrc + (sseg + 32)*4);
      f16x4 hv;
      hv[0] = (f16)xv0.x; hv[1] = (f16)xv0.y; hv[2] = (f16)xv0.z; hv[3] = (f16)xv0.w;
      *(f16x4*)(smem + Abase + ((srow*2560u + 2048u + 8u*(u32)(sseg     )) ^ swzr)) = hv;
      hv[0] = (f16)xv1.x; hv[1] = (f16)xv1.y; hv[2] = (f16)xv1.z; hv[3] = (f16)xv1.w;
      *(f16x4*)(smem + Abase + ((srow*2560u + 2048u + 8u*(u32)(sseg + 32)) ^ swzr)) = hv;
    }
    // ---- tile-T barrier: all 32 blocks finished tile-T step s-1
    if (s > 0) {
      if (wv == 0) {
        if (!preOK) {
          const u32 tgt = (u32)s;
          u32 v = tgt;
          int guard = 0;
          for (;;) {
            if (lane < 32)
              v = __hip_atomic_load(flgT + lane, __ATOMIC_RELAXED,
                                    __HIP_MEMORY_SCOPE_AGENT);
            if (__all(v >= tgt)) break;
            __builtin_amdgcn_s_sleep(1);
            if (++guard > (1 << 18)) break;
          }
        }
        if (lane == 0) {
          if (xloc) {
            asm volatile("buffer_inv sc0\n\ts_waitcnt vmcnt(0)" ::: "memory");
          } else {
            __threadfence();
          }
        }
      }
    }
    __syncthreads();
    // ---- stage tile-T h part [16 rows x 1024] fp16, XOR-swizzled (4-bit)
    {
      const f16* hsrc = hbuf + (size_t)(s & 1)*262144 + (size_t)grow*1024;
#pragma unroll
      for (int j = 0; j < 4; ++j) {
        int chunk = sseg + 32*j;                       // 16B chunk of h row
        uint4 v = *(const uint4*)(hsrc + chunk*8);
        *(uint4*)(smem + Abase + ((srow*2560u + 16u*(u32)chunk) ^ swzr)) = v;
      }
    }
    __syncthreads();
    // ---- early poll: issue next slot's flag loads now, consume after gates
    {
      const int nT = (slot + 1) & 1, nS = (slot + 1) >> 1;
      pre = 0xFFFFFFFFu;
      if (wv == 0 && nS > 0 && nS < 512 && lane < 32)
        pre = __hip_atomic_load(flg + nT*32 + lane, __ATOMIC_RELAXED,
                                __HIP_MEMORY_SCOPE_AGENT);
    }
    // ---- K loop: half-K (640) per wave, 16 rows, 32 z-cols (2 frags/chains)
    f32x4 acc0 = {}, acc1 = {};
#pragma unroll
    for (int kk = 0; kk < 20; ++kk) {
      f16x8 av = *(const f16x8*)(smem + Abase + ((aoff + (u32)kk*64u) ^ aswz));
      acc0 = __builtin_amdgcn_mfma_f32_16x16x32_f16(av, Breg[kk][0], acc0, 0, 0, 0);
      acc1 = __builtin_amdgcn_mfma_f32_16x16x32_f16(av, Breg[kk][1], acc1, 0, 0, 0);
    }
    // partial z write: zbuf[T][kh][gate][row][col], cols l15 and l15+16
    {
      const u32 zb = ZBASE + (u32)T*24576u + (u32)kh*ZKH + (u32)gate*ZGATE
                   + (u32)l15*4u;
#pragma unroll
      for (int i = 0; i < 4; ++i) {
        u32 r0 = (u32)(l4*4 + i);
        *(float*)(smem + zb + r0*ZROW)       = acc0[i];
        *(float*)(smem + zb + r0*ZROW + 64u) = acc1[i];
      }
    }
    __syncthreads();
    // ---- gates + c/h update (512 threads x 1 elem: row tid>>5, col tid&31)
    {
      f16* hw = hbuf + (size_t)((s & 1) ^ 1)*262144;
      const int row = tid >> 5, col = tid & 31;
      const int gcol = cg*32 + col;
      const u32 zo = ZBASE + (u32)T*24576u + (u32)row*ZROW + (u32)col*4u;
      float zg = *(const float*)(smem + zo + 0u*ZGATE)
               + *(const float*)(smem + zo + 0u*ZGATE + ZKH) + bgr;
      float zi = *(const float*)(smem + zo + 1u*ZGATE)
               + *(const float*)(smem + zo + 1u*ZGATE + ZKH) + bir;
      float zf = *(const float*)(smem + zo + 2u*ZGATE)
               + *(const float*)(smem + zo + 2u*ZGATE + ZKH) + bfr;
      float zv = *(const float*)(smem + zo + 3u*ZGATE)
               + *(const float*)(smem + zo + 3u*ZGATE + ZKH) + bor;
      float* cp = (float*)(smem + CBUF + (u32)T*2048u + (u32)(row*32 + col)*4u);
      float cv = *cp;
      float gv = tanhfast(zg);
      float iv = sigm(zi);
      float fv = sigm(zf);
      float ov = sigm(zv);
      float cn = gv*iv + cv*fv;
      *cp = cn;
      hw[(size_t)(xg*32 + T*16 + row)*1024 + gcol] = (f16)(tanhfast(cn) * ov);
    }
    __syncthreads();   // drains h stores (vmcnt) before flag release
    if (tid == 0) {
      if (!xloc) __threadfence();
      __hip_atomic_store(flgT + cg, (u32)(s + 1),
                         __ATOMIC_RELAXED, __HIP_MEMORY_SCOPE_AGENT);
    }
    if (wv == 0) {
      const int nS = (slot + 1) >> 1;
      preOK = (nS == 0) || (nS >= 512) || __all(pre >= (u32)nS);
    }
  }

  // ---- epilogue: wait both tiles at 512, logits = h @ WphT + bp
  if (wv == 0) {
    u32 v = 512u;
    int guard = 0;
    for (;;) {
      v = __hip_atomic_load(flg + lane, __ATOMIC_RELAXED,
                            __HIP_MEMORY_SCOPE_AGENT);   // lanes 0-63 = A,B
      if (__all(v >= 512u)) break;
      __builtin_amdgcn_s_sleep(1);
      if (++guard > (1 << 18)) break;
    }
    if (lane == 0) {
      if (xloc) { asm volatile("buffer_inv sc0\n\ts_waitcnt vmcnt(0)" ::: "memory"); }
      else      { __threadfence(); }
    }
  }
  __syncthreads();
  {
#pragma unroll 1
    for (int p = 0; p < 32; ++p) {
      int rowl = wv*4 + (p >> 3);
      int oc   = p & 7;
      const f16* hp = hbuf + (size_t)(xg*32 + rowl)*1024 + lane*16;  // buf 0 = h_T
      const f16* wp = WphT + (size_t)(cg*8 + oc)*1024 + lane*16;
      f16x8 h0 = *(const f16x8*)hp;
      f16x8 h1 = *(const f16x8*)(hp + 8);
      f16x8 w0 = *(const f16x8*)wp;
      f16x8 w1 = *(const f16x8*)(wp + 8);
      float sum = 0.f;
#pragma unroll
      for (int q = 0; q < 8; ++q)
        sum += (float)h0[q]*(float)w0[q] + (float)h1[q]*(float)w1[q];
#pragma unroll
      for (int d = 1; d < 64; d <<= 1) sum += __shfl_xor(sum, d);
      if (lane == 0)
        lg[(size_t)(xg*32 + rowl)*256 + cg*8 + oc] = sum + bpp[cg*8 + oc];
    }
  }
  __syncthreads();   // drain lg stores
  if (tid == 0) {
    if (!xloc) __threadfence();
    __hip_atomic_store(flg + cg, 513u, __ATOMIC_RELAXED, __HIP_MEMORY_SCOPE_AGENT);
  }
  if (wv == 0) {
    u32 v = 513u;
    int guard = 0;
    for (;;) {
      if (lane < 32)
        v = __hip_atomic_load(flg + lane, __ATOMIC_RELAXED, __HIP_MEMORY_SCOPE_AGENT);
      if (__all(v >= 513u)) break;
      __builtin_amdgcn_s_sleep(1);
      if (++guard > (1 << 18)) break;
    }
    if (lane == 0) {
      if (xloc) { asm volatile("buffer_inv sc0\n\ts_waitcnt vmcnt(0)" ::: "memory"); }
      else      { __threadfence(); }
    }
  }
  __syncthreads();
  // ---- softmax: this block handles row xg*32+cg, wave 0 only
  if (tid < 64) {
    int rowg = xg*32 + cg;
    const float* lr = lg + (size_t)rowg*256;
    float v0 = lr[tid], v1 = lr[tid+64], v2 = lr[tid+128], v3 = lr[tid+192];
    float mx = fmaxf(fmaxf(v0, v1), fmaxf(v2, v3));
#pragma unroll
    for (int d = 1; d < 64; d <<= 1) mx = fmaxf(mx, __shfl_xor(mx, d));
    float e0 = __expf(v0-mx), e1 = __expf(v1-mx), e2 = __expf(v2-mx), e3 = __expf(v3-mx);
    float sm = e0+e1+e2+e3;
#pragma unroll
    for (int d = 1; d < 64; d <<= 1) sm += __shfl_xor(sm, d);
    float inv = 1.0f / sm;
    float* orow = out + (size_t)rowg*256;
    orow[tid]      = e0*inv;
    orow[tid+64]   = e1*inv;
    orow[tid+128]  = e2*inv;
    orow[tid+192]  = e3*inv;
  }
}

extern "C" void kernel_launch(void* const* d_in, const int* in_sizes, int n_in,
                              void* d_out, int out_size, void* d_ws, size_t ws_size,
                              hipStream_t stream) {
  (void)in_sizes; (void)n_in; (void)out_size; (void)ws_size;
  const float* x   = (const float*)d_in[0];
  const float* Wgx = (const float*)d_in[1];
  const float* Wgh = (const float*)d_in[2];
  const float* bg  = (const float*)d_in[3];
  const float* Wix = (const float*)d_in[4];
  const float* Wih = (const float*)d_in[5];
  const float* bi  = (const float*)d_in[6];
  const float* Wfx = (const float*)d_in[7];
  const float* Wfh = (const float*)d_in[8];
  const float* bf  = (const float*)d_in[9];
  const float* Wox = (const float*)d_in[10];
  const float* Woh = (const float*)d_in[11];
  const float* bo  = (const float*)d_in[12];
  const float* Wph = (const float*)d_in[13];
  const float* bp  = (const float*)d_in[14];

  char* ws = (char*)d_ws;
  f16*   WT   = (f16*)(ws + WS_WT);
  f16*   WphT = (f16*)(ws + WS_WPHT);
  f16*   hbuf = (f16*)(ws + WS_HBUF);
  float* lg   = (float*)(ws + WS_LG);
  u32*   cnt  = (u32*)(ws + WS_CNT);
  u32*   tick = (u32*)(ws + WS_TICK);

  // h0 = 0 (buffer 0); flags + tickets = 0 (replay-safe)
  hipMemsetAsync(hbuf, 0, 524288, stream);
  hipMemsetAsync(cnt, 0, 2048 + 64, stream);

  prep_wt<<<5120, 256, 0, stream>>>(Wgh, Wih, Wfh, Woh, Wgx, Wix, Wfx, Wox, WT);
  prep_wph<<<256, 256, 0, stream>>>(Wph, WphT);
  lstm_main<<<256, 512, 0, stream>>>(x, WT, WphT, hbuf,
                                     bg, bi, bf, bo, bp,
                                     lg, cnt, tick, (float*)d_out);
}

// Round 12
// 2485.002 us; speedup vs baseline: 1.9622x; 1.0080x over previous
//
#include <hip/hip_runtime.h>

// LSTM fused kernel for MI355X (gfx950) — round 12: transposed MFMA (gates in
// lanes) + K-split-4 + vectorized zbuf + per-wave barrier (3 syncs/slot).
// 256 blocks x 512 threads (8 waves, 2/SIMD). Group = measured XCD; 32 batch
// rows split into tiles A/B (16 rows) alternated per slot.
// Wave w = (hgrp=w&1, kh=w>>1): 16 h-cols x 4 gates x K/4. MFMA computes
// z^T: A-op = W frag (m = hcolsub*4+gate, gate-minor), B-op = activations
// (n = batch row). Lane (l15=row, l4): acc[f][i] = gate i of h-col
// hgrp*16+f*4+l4. Cross-kh reduction via single 32KB zbuf, f32x4 ops.
// c in registers. Sync: per-wave spin + per-wave L1-inv (deferred to
// end-of-slot when early-poll confirms); 3 syncthreads/slot.
// Workspace (~12.4 MB): WT fp16 [4096][1280] @0, WphT @10485760,
// hbuf [2][256][1024] @11010048, lg @12058624, cnt @12320768, tick @12322816

typedef _Float16 f16;
typedef _Float16 f16x8 __attribute__((ext_vector_type(8)));
typedef _Float16 f16x4 __attribute__((ext_vector_type(4)));
typedef float f32x4 __attribute__((ext_vector_type(4)));
typedef unsigned int u32;

#define WS_WT    0
#define WS_WPHT  10485760
#define WS_HBUF  11010048
#define WS_LG    12058624
#define WS_CNT   12320768
#define WS_TICK  12322816

// LDS: A-tile[2] [16][2560B] @0/@40960; zbuf [kh4][512 slots x 16B] @81920
// (32 KB, slot16 = (row*32+hcol) ^ (row&7)); bcast @114688.
#define ZB    81920u
#define BCAST 114688

__device__ __forceinline__ float sigm(float v) { return 1.0f / (1.0f + __expf(-v)); }
__device__ __forceinline__ float tanhfast(float v) {
  float t = __expf(-2.0f * fabsf(v));
  float r = (1.0f - t) / (1.0f + t);
  return v < 0.0f ? -r : r;
}

// ---------- prep: WT[n][k], n=gate*1024+j (z-col), k<1024 -> Wh[k][j], else Wx[k-1024][j]
__global__ __launch_bounds__(256) void prep_wt(
    const float* __restrict__ Wgh, const float* __restrict__ Wih,
    const float* __restrict__ Wfh, const float* __restrict__ Woh,
    const float* __restrict__ Wgx, const float* __restrict__ Wix,
    const float* __restrict__ Wfx, const float* __restrict__ Wox,
    f16* __restrict__ WT)
{
  __shared__ float tile[32][33];
  int bid = blockIdx.x;
  int gate = bid / 1280;
  int rem  = bid % 1280;
  int jt = rem / 40, kt = rem % 40;
  const float* srcH = (gate==0)?Wgh:(gate==1)?Wih:(gate==2)?Wfh:Woh;
  const float* srcX = (gate==0)?Wgx:(gate==1)?Wix:(gate==2)?Wfx:Wox;
  const float* src = (kt < 32) ? (srcH + (size_t)(kt*32)*1024)
                               : (srcX + (size_t)(kt*32 - 1024)*1024);
  int t = threadIdx.x;
  {
    int jl = t & 31, kg = t >> 5;
#pragma unroll
    for (int it = 0; it < 4; ++it) {
      int kl = kg + it*8;
      tile[kl][jl] = src[(size_t)kl*1024 + jt*32 + jl];
    }
  }
  __syncthreads();
  {
    int kl = t & 31, jg = t >> 5;
#pragma unroll
    for (int it = 0; it < 4; ++it) {
      int jl2 = jg + it*8;
      WT[(size_t)(gate*1024 + jt*32 + jl2)*1280 + kt*32 + kl] = (f16)tile[kl][jl2];
    }
  }
}

// ---------- prep: WphT[oc][k] = W_ph[k][oc], fp16
__global__ __launch_bounds__(256) void prep_wph(const float* __restrict__ Wph,
                                                f16* __restrict__ WphT)
{
  __shared__ float tile[32][33];
  int bid = blockIdx.x;
  int jt = bid & 7, kt = bid >> 3;
  int t = threadIdx.x;
  {
    int jl = t & 31, kg = t >> 5;
#pragma unroll
    for (int it = 0; it < 4; ++it) {
      int kl = kg + it*8;
      tile[kl][jl] = Wph[(size_t)(kt*32 + kl)*256 + jt*32 + jl];
    }
  }
  __syncthreads();
  {
    int kl = t & 31, jg = t >> 5;
#pragma unroll
    for (int it = 0; it < 4; ++it) {
      int jl2 = jg + it*8;
      WphT[(size_t)(jt*32 + jl2)*1024 + kt*32 + kl] = (f16)tile[kl][jl2];
    }
  }
}

// ---------- main persistent LSTM kernel
__global__ __launch_bounds__(512, 2) void lstm_main(
    const float* __restrict__ x, const f16* __restrict__ WT,
    const f16* __restrict__ WphT, f16* __restrict__ hbuf,
    const float* __restrict__ bgp, const float* __restrict__ bip,
    const float* __restrict__ bfp, const float* __restrict__ bop,
    const float* __restrict__ bpp, float* __restrict__ lg,
    u32* __restrict__ cnt, u32* __restrict__ tick, float* __restrict__ out)
{
  __shared__ __align__(16) char smem[114704];
  const int tid  = threadIdx.x;
  const int lane = tid & 63;
  const int wv   = tid >> 6;
  const int hgrp = wv & 1;         // h-col half (16 cols)
  const int kh   = wv >> 1;        // K quarter (320)
  const int l15 = lane & 15, l4 = lane >> 4;

  // ---- measure XCD, take ticket on per-XCD counter
  u32 myxcd;
  asm volatile("s_getreg_b32 %0, hwreg(HW_REG_XCC_ID)" : "=s"(myxcd));
  myxcd &= 7u;
  if (tid == 0) {
    u32 t = __hip_atomic_fetch_add(tick + myxcd, 1u,
                                   __ATOMIC_RELAXED, __HIP_MEMORY_SCOPE_AGENT);
    *(volatile u32*)(smem + BCAST) = t;
  }
  if (wv == 0) {
    u32 v = 0;
    int guard = 0;
    for (;;) {
      v = (lane < 8) ? __hip_atomic_load(tick + lane, __ATOMIC_RELAXED,
                                         __HIP_MEMORY_SCOPE_AGENT) : 0u;
      u32 sum = v;
      sum += __shfl_xor(sum, 1);
      sum += __shfl_xor(sum, 2);
      sum += __shfl_xor(sum, 4);
      if (__shfl(sum, 0) == 256u) break;
      __builtin_amdgcn_s_sleep(1);
      if (++guard > (1 << 20)) break;
    }
    int even = __all((lane < 8) ? (v == 32u) : 1);
    if (lane == 0) *(volatile u32*)(smem + BCAST + 4) = (u32)even;
  }
  __syncthreads();
  const bool xloc = (*(volatile u32*)(smem + BCAST + 4)) != 0u;
  const u32 myticket = *(volatile u32*)(smem + BCAST);
  const int xg = xloc ? (int)myxcd    : (blockIdx.x & 7);   // batch-tile group
  const int cg = xloc ? (int)myticket : (blockIdx.x >> 3);  // column slice 0..31
  u32* flg = cnt + xg*64;           // [tileA flags 0..31][tileB flags 32..63]

  // ---- weight-stationary A-op fragments: [10 kk][4 frags] = 160 regs.
  // Lane l15 = m = hcolsub*4 + gate (gate-minor interleave).
  f16x8 Breg[10][4];
  {
    const int gate = l15 & 3, hsub = l15 >> 2;
#pragma unroll
    for (int f = 0; f < 4; ++f) {
      const int n = gate*1024 + cg*32 + hgrp*16 + f*4 + hsub;
      const f16* wb = WT + (size_t)n*1280 + kh*320 + l4*8;
#pragma unroll
      for (int kk = 0; kk < 10; ++kk) {
        Breg[kk][f] = *(const f16x8*)(wb + kk*32);
        asm volatile("" : "+v"(Breg[kk][f]));   // pin: no remat
      }
    }
  }

  // per-thread bias (gates phase handles hcol = tid&31)
  const int bcol = cg*32 + (tid & 31);
  const float bgr = bgp[bcol], bir = bip[bcol], bfr = bfp[bcol], bor = bop[bcol];

  // activation (B-op) frag addressing: lane l15 = batch row, k = kh*320+kk*32+l4*8
  const u32 aoff = (u32)l15*2560u + (u32)(kh*640 + l4*16);
  const u32 aswz = (u32)l15 << 4;
  // staging indices: 16 rows x 32 segs (512 threads), 4-bit swizzle
  const int srow = tid >> 5;
  const int sseg = tid & 31;
  const u32 swzr = (u32)srow << 4;

  // c state in registers (gates-phase thread owns (row=tid>>5, hcol=tid&31))
  float cA = 0.0f, cB = 0.0f;

  u32 pre = 0xFFFFFFFFu;
  bool preOK = false;

#pragma unroll 1
  for (int slot = 0; slot < 1024; ++slot) {
    const int T = slot & 1, s = slot >> 1;
    const u32 Abase = (u32)T * 40960u;
    u32* flgT = flg + T*32;
    const int grow = xg*32 + T*16 + srow;

    // ---- x stage (tile-T x region dead since slot-2) — overlaps flag latency
    {
      const float* xsrc = x + ((size_t)grow*512 + (size_t)s)*256;
      float4 xv0 = *(const float4*)(xsrc + (sseg     )*4);
      float4 xv1 = *(const float4*)(xsrc + (sseg + 32)*4);
      f16x4 hv;
      hv[0] = (f16)xv0.x; hv[1] = (f16)xv0.y; hv[2] = (f16)xv0.z; hv[3] = (f16)xv0.w;
      *(f16x4*)(smem + Abase + ((srow*2560u + 2048u + 8u*(u32)(sseg     )) ^ swzr)) = hv;
      hv[0] = (f16)xv1.x; hv[1] = (f16)xv1.y; hv[2] = (f16)xv1.z; hv[3] = (f16)xv1.w;
      *(f16x4*)(smem + Abase + ((srow*2560u + 2048u + 8u*(u32)(sseg + 32)) ^ swzr)) = hv;
    }
    // ---- per-wave barrier: only if this wave's early-poll didn't confirm
    if (s > 0 && !preOK) {
      const u32 tgt = (u32)s;
      u32 v = tgt;
      int guard = 0;
      for (;;) {
        if (lane < 32)
          v = __hip_atomic_load(flgT + lane, __ATOMIC_RELAXED,
                                __HIP_MEMORY_SCOPE_AGENT);
        if (__all(v >= tgt)) break;
        __builtin_amdgcn_s_sleep(1);
        if (++guard > (1 << 18)) break;
      }
      if (lane == 0) {
        if (xloc) { asm volatile("buffer_inv sc0\n\ts_waitcnt vmcnt(0)" ::: "memory"); }
        else      { __threadfence(); }
      }
    }
    // ---- stage tile-T h part [16 rows x 1024] fp16, XOR-swizzled
    {
      const f16* hsrc = hbuf + (size_t)(s & 1)*262144 + (size_t)grow*1024;
#pragma unroll
      for (int j = 0; j < 4; ++j) {
        int chunk = sseg + 32*j;
        uint4 v = *(const uint4*)(hsrc + chunk*8);
        *(uint4*)(smem + Abase + ((srow*2560u + 16u*(u32)chunk) ^ swzr)) = v;
      }
    }
    __syncthreads();   // (A) staging complete
    // ---- K loop: K/4 per wave; one av feeds 4 col-frags (gates in lanes)
    f32x4 acc0 = {}, acc1 = {}, acc2 = {}, acc3 = {};
#pragma unroll
    for (int kk = 0; kk < 10; ++kk) {
      f16x8 av = *(const f16x8*)(smem + Abase + ((aoff + (u32)kk*64u) ^ aswz));
      acc0 = __builtin_amdgcn_mfma_f32_16x16x32_f16(Breg[kk][0], av, acc0, 0, 0, 0);
      acc1 = __builtin_amdgcn_mfma_f32_16x16x32_f16(Breg[kk][1], av, acc1, 0, 0, 0);
      acc2 = __builtin_amdgcn_mfma_f32_16x16x32_f16(Breg[kk][2], av, acc2, 0, 0, 0);
      acc3 = __builtin_amdgcn_mfma_f32_16x16x32_f16(Breg[kk][3], av, acc3, 0, 0, 0);
    }
    // ---- early poll (ALL waves): next slot's flags, consumed after gates
    {
      const int nT = (slot + 1) & 1, nS = (slot + 1) >> 1;
      pre = 0xFFFFFFFFu;
      if (nS > 0 && nS < 512 && lane < 32)
        pre = __hip_atomic_load(flg + nT*32 + lane, __ATOMIC_RELAXED,
                                __HIP_MEMORY_SCOPE_AGENT);
    }
    // ---- zbuf partial write: f32x4 (4 gates) at slot16=(row*32+hcol)^(row&7)
    {
      const u32 zkh = ZB + (u32)kh*8192u;
#pragma unroll
      for (int f = 0; f < 4; ++f) {
        const u32 hcol = (u32)(hgrp*16 + f*4 + l4);
        const u32 s16 = ((u32)(l15*32) + hcol) ^ ((u32)(l15 & 7));
        f32x4 acc = (f==0)?acc0:(f==1)?acc1:(f==2)?acc2:acc3;
        *(f32x4*)(smem + zkh + s16*16u) = acc;
      }
    }
    __syncthreads();   // (B) zbuf ready
    // ---- gates: thread (row=tid>>5, hcol=tid&31), all lanes active
    {
      f16* hw = hbuf + (size_t)((s & 1) ^ 1)*262144;
      const int row = tid >> 5, hcol = tid & 31;
      const u32 s16 = ((u32)(row*32) + (u32)hcol) ^ ((u32)(row & 7));
      const u32 ro = s16*16u;
      f32x4 z0 = *(const f32x4*)(smem + ZB +        ro);
      f32x4 z1 = *(const f32x4*)(smem + ZB + 8192u  + ro);
      f32x4 z2 = *(const f32x4*)(smem + ZB + 16384u + ro);
      f32x4 z3 = *(const f32x4*)(smem + ZB + 24576u + ro);
      float zg = z0[0] + z1[0] + z2[0] + z3[0] + bgr;
      float zi = z0[1] + z1[1] + z2[1] + z3[1] + bir;
      float zf = z0[2] + z1[2] + z2[2] + z3[2] + bfr;
      float zo = z0[3] + z1[3] + z2[3] + z3[3] + bor;
      float cv = T ? cB : cA;
      float gv = tanhfast(zg);
      float iv = sigm(zi);
      float fv = sigm(zf);
      float ov = sigm(zo);
      float cn = gv*iv + cv*fv;
      if (T) cB = cn; else cA = cn;
      hw[(size_t)(xg*32 + T*16 + row)*1024 + cg*32 + hcol] = (f16)(tanhfast(cn) * ov);
    }
    // ---- preOK eval + deferred inv (per wave)
    {
      const int nS = (slot + 1) >> 1;
      bool ok = (nS >= 512) || __all(pre >= (u32)nS);
      preOK = xloc && ok;
      if (preOK && nS < 512 && lane == 0) {
        asm volatile("buffer_inv sc0\n\ts_waitcnt vmcnt(0)" ::: "memory");
      }
    }
    __syncthreads();   // (C) drains h stores + orders inv before next slot
    if (tid == 0) {
      if (!xloc) __threadfence();
      __hip_atomic_store(flgT + cg, (u32)(s + 1),
                         __ATOMIC_RELAXED, __HIP_MEMORY_SCOPE_AGENT);
    }
  }

  // ---- epilogue: wait both tiles at 512, logits = h @ WphT + bp
  if (wv == 0) {
    u32 v = 512u;
    int guard = 0;
    for (;;) {
      v = __hip_atomic_load(flg + lane, __ATOMIC_RELAXED,
                            __HIP_MEMORY_SCOPE_AGENT);   // lanes 0-63 = A,B
      if (__all(v >= 512u)) break;
      __builtin_amdgcn_s_sleep(1);
      if (++guard > (1 << 18)) break;
    }
    if (lane == 0) {
      if (xloc) { asm volatile("buffer_inv sc0\n\ts_waitcnt vmcnt(0)" ::: "memory"); }
      else      { __threadfence(); }
    }
  }
  __syncthreads();
  {
#pragma unroll 1
    for (int p = 0; p < 32; ++p) {
      int rowl = wv*4 + (p >> 3);
      int oc   = p & 7;
      const f16* hp = hbuf + (size_t)(xg*32 + rowl)*1024 + lane*16;  // buf 0 = h_T
      const f16* wp = WphT + (size_t)(cg*8 + oc)*1024 + lane*16;
      f16x8 h0 = *(const f16x8*)hp;
      f16x8 h1 = *(const f16x8*)(hp + 8);
      f16x8 w0 = *(const f16x8*)wp;
      f16x8 w1 = *(const f16x8*)(wp + 8);
      float sum = 0.f;
#pragma unroll
      for (int q = 0; q < 8; ++q)
        sum += (float)h0[q]*(float)w0[q] + (float)h1[q]*(float)w1[q];
#pragma unroll
      for (int d = 1; d < 64; d <<= 1) sum += __shfl_xor(sum, d);
      if (lane == 0)
        lg[(size_t)(xg*32 + rowl)*256 + cg*8 + oc] = sum + bpp[cg*8 + oc];
    }
  }
  __syncthreads();   // drain lg stores
  if (tid == 0) {
    if (!xloc) __threadfence();
    __hip_atomic_store(flg + cg, 513u, __ATOMIC_RELAXED, __HIP_MEMORY_SCOPE_AGENT);
  }
  if (wv == 0) {
    u32 v = 513u;
    int guard = 0;
    for (;;) {
      if (lane < 32)
        v = __hip_atomic_load(flg + lane, __ATOMIC_RELAXED, __HIP_MEMORY_SCOPE_AGENT);
      if (__all(v >= 513u)) break;
      __builtin_amdgcn_s_sleep(1);
      if (++guard > (1 << 18)) break;
    }
    if (lane == 0) {
      if (xloc) { asm volatile("buffer_inv sc0\n\ts_waitcnt vmcnt(0)" ::: "memory"); }
      else      { __threadfence(); }
    }
  }
  __syncthreads();
  // ---- softmax: this block handles row xg*32+cg, wave 0 only
  if (tid < 64) {
    int rowg = xg*32 + cg;
    const float* lr = lg + (size_t)rowg*256;
    float v0 = lr[tid], v1 = lr[tid+64], v2 = lr[tid+128], v3 = lr[tid+192];
    float mx = fmaxf(fmaxf(v0, v1), fmaxf(v2, v3));
#pragma unroll
    for (int d = 1; d < 64; d <<= 1) mx = fmaxf(mx, __shfl_xor(mx, d));
    float e0 = __expf(v0-mx), e1 = __expf(v1-mx), e2 = __expf(v2-mx), e3 = __expf(v3-mx);
    float sm = e0+e1+e2+e3;
#pragma unroll
    for (int d = 1; d < 64; d <<= 1) sm += __shfl_xor(sm, d);
    float inv = 1.0f / sm;
    float* orow = out + (size_t)rowg*256;
    orow[tid]      = e0*inv;
    orow[tid+64]   = e1*inv;
    orow[tid+128]  = e2*inv;
    orow[tid+192]  = e3*inv;
  }
}

extern "C" void kernel_launch(void* const* d_in, const int* in_sizes, int n_in,
                              void* d_out, int out_size, void* d_ws, size_t ws_size,
                              hipStream_t stream) {
  (void)in_sizes; (void)n_in; (void)out_size; (void)ws_size;
  const float* x   = (const float*)d_in[0];
  const float* Wgx = (const float*)d_in[1];
  const float* Wgh = (const float*)d_in[2];
  const float* bg  = (const float*)d_in[3];
  const float* Wix = (const float*)d_in[4];
  const float* Wih = (const float*)d_in[5];
  const float* bi  = (const float*)d_in[6];
  const float* Wfx = (const float*)d_in[7];
  const float* Wfh = (const float*)d_in[8];
  const float* bf  = (const float*)d_in[9];
  const float* Wox = (const float*)d_in[10];
  const float* Woh = (const float*)d_in[11];
  const float* bo  = (const float*)d_in[12];
  const float* Wph = (const float*)d_in[13];
  const float* bp  = (const float*)d_in[14];

  char* ws = (char*)d_ws;
  f16*   WT   = (f16*)(ws + WS_WT);
  f16*   WphT = (f16*)(ws + WS_WPHT);
  f16*   hbuf = (f16*)(ws + WS_HBUF);
  float* lg   = (float*)(ws + WS_LG);
  u32*   cnt  = (u32*)(ws + WS_CNT);
  u32*   tick = (u32*)(ws + WS_TICK);

  // h0 = 0 (buffer 0); flags + tickets = 0 (replay-safe)
  hipMemsetAsync(hbuf, 0, 524288, stream);
  hipMemsetAsync(cnt, 0, 2048 + 64, stream);

  prep_wt<<<5120, 256, 0, stream>>>(Wgh, Wih, Wfh, Woh, Wgx, Wix, Wfx, Wox, WT);
  prep_wph<<<256, 256, 0, stream>>>(Wph, WphT);
  lstm_main<<<256, 512, 0, stream>>>(x, WT, WphT, hbuf,
                                     bg, bi, bf, bo, bp,
                                     lg, cnt, tick, (float*)d_out);
}